// Round 1
// baseline (48.381 us; speedup 1.0000x reference)
//
#include <hip/hip_runtime.h>
#include <cstdint>

#define DEVFN __device__ __forceinline__

struct U128 { unsigned long long lo, hi; };

// rotate right by s (1..127): bit q of result = bit (q+s)%128 of w
DEVFN U128 rotr128(U128 w, int s) {
    U128 r;
    if (s == 64) { r.lo = w.hi; r.hi = w.lo; return r; }
    if (s < 64) {
        r.lo = (w.lo >> s) | (w.hi << (64 - s));
        r.hi = (w.hi >> s) | (w.lo << (64 - s));
    } else {
        int t = s - 64;
        unsigned long long lo = w.hi, hi = w.lo; // rotr 64 first
        r.lo = (lo >> t) | (hi << (64 - t));
        r.hi = (hi >> t) | (lo << (64 - t));
    }
    return r;
}

// logical shift right by s (1..127): bit j of result = bit (j+s) of w (0 beyond)
DEVFN U128 shr128(U128 w, int s) {
    U128 r;
    if (s == 64) { r.lo = w.hi; r.hi = 0ull; return r; }
    if (s < 64) {
        r.lo = (w.lo >> s) | (w.hi << (64 - s));
        r.hi = w.hi >> s;
    } else {
        r.lo = w.hi >> (s - 64); r.hi = 0ull;
    }
    return r;
}

// K1: S[b][r] = 2 * (r==0 ? pc_r : 128 - pc_r), pc_r = popcount(Dc^r(x_b))
__global__ __launch_bounds__(512) void k1_S(const int* __restrict__ x, float* __restrict__ S) {
    int tid = threadIdx.x;      // 512 threads: b = tid>>3 (64), rchunk = tid&7 (8)
    int b = tid >> 3;
    int rc = tid & 7;
    const int* xb = x + b * 128;
    U128 w; w.lo = 0ull; w.hi = 0ull;
    #pragma unroll
    for (int p = 0; p < 64; ++p) w.lo |= (unsigned long long)(xb[p] & 1) << p;
    #pragma unroll
    for (int p = 0; p < 64; ++p) w.hi |= (unsigned long long)(xb[64 + p] & 1) << p;
    int r0 = rc * 16;
    if (r0 & 16) { U128 t = rotr128(w, 16); w.lo ^= t.lo; w.hi ^= t.hi; }
    if (r0 & 32) { U128 t = rotr128(w, 32); w.lo ^= t.lo; w.hi ^= t.hi; }
    if (r0 & 64) { U128 t = rotr128(w, 64); w.lo ^= t.lo; w.hi ^= t.hi; }
    for (int rr = 0; rr < 16; ++rr) {
        int r = r0 + rr;
        int pc = __popcll(w.lo) + __popcll(w.hi);
        int sv = (r == 0) ? pc : (128 - pc);
        S[b * 128 + r] = (float)(2 * sv);
        U128 t = rotr128(w, 1);
        w.lo ^= t.lo; w.hi ^= t.hi;
    }
}

// K2: reduce W0 (8256x1024) into Apart[128][1024], G[128][1024]
// Apart[r][h] = sum_j (c/2 - 1) * W0[(r,j),h]; G[r][h] = sum_j (2-c)/256 * W0[(r,j),h]
__global__ __launch_bounds__(256) void k2_reduceW0(const float* __restrict__ W0,
                                                   const int* __restrict__ masks,
                                                   float* __restrict__ Apart,
                                                   float* __restrict__ G) {
    int r  = blockIdx.y;            // 0..127
    int ht = blockIdx.x;            // 0..3
    int tid = threadIdx.x;          // 0..255
    int h = ht * 256 + tid;
    int L = 128 - r;

    __shared__ unsigned long long mw[3][2];
    __shared__ float cA[128], cG[128];

    if (tid < 128) {                // two full waves -> ballot is safe
        int half = tid >> 6;
        int lane = tid & 63;
        #pragma unroll
        for (int k = 0; k < 3; ++k) {
            unsigned long long bal = __ballot(masks[k * 128 + half * 64 + lane] & 1);
            if (lane == 0) mw[k][half] = bal;
        }
    }
    __syncthreads();
    if (tid < 128) {
        int j = tid;
        int c = 0;
        #pragma unroll
        for (int k = 0; k < 3; ++k) {
            U128 m; m.lo = mw[k][0]; m.hi = mw[k][1];
            // jump mask derivative to level r: D^(2^s)(m) = m ^ (m >> 2^s)
            #pragma unroll
            for (int s = 1; s <= 64; s <<= 1) {
                if (r & s) { U128 t = shr128(m, s); m.lo ^= t.lo; m.hi ^= t.hi; }
            }
            int bit = (j < 64) ? (int)((m.lo >> j) & 1) : (int)((m.hi >> (j - 64)) & 1);
            c += bit;
        }
        cA[j] = 0.5f * (float)c - 1.0f;
        cG[j] = (float)(2 - c) * (1.0f / 256.0f);
    }
    __syncthreads();

    int off = r * 128 - (r * (r - 1)) / 2;        // row offset in t
    const float* p = W0 + off * 1024 + h;
    float accA = 0.f, accG = 0.f;
    #pragma unroll 4
    for (int j = 0; j < L; ++j) {
        float w = p[j * 1024];
        accA += cA[j] * w;
        accG += cG[j] * w;
    }
    Apart[r * 1024 + h] = accA;
    G[r * 1024 + h]     = accG;
}

// K3: h0[b][h] = relu(b0[h] + sum_r (Apart[r][h] + S[b][r]*G[r][h]))
__global__ __launch_bounds__(256) void k3_layer1(const float* __restrict__ Apart,
                                                 const float* __restrict__ G,
                                                 const float* __restrict__ S,
                                                 const float* __restrict__ b0,
                                                 float* __restrict__ h0) {
    int b  = blockIdx.x;           // 64
    int ht = blockIdx.y;           // 4
    int tid = threadIdx.x;
    int h = ht * 256 + tid;
    __shared__ float Srow[128];
    if (tid < 128) Srow[tid] = S[b * 128 + tid];
    __syncthreads();
    float acc = b0[h];
    #pragma unroll 8
    for (int r = 0; r < 128; ++r) {
        acc += Apart[r * 1024 + h] + Srow[r] * G[r * 1024 + h];
    }
    h0[b * 1024 + h] = fmaxf(acc, 0.f);
}

// K4: split-K GEMM partials: z1part[kc][b][h] = sum_{k in chunk} h0[b][k] * W1[k][h]
__global__ __launch_bounds__(256) void k4_layer2(const float* __restrict__ h0,
                                                 const float* __restrict__ W1,
                                                 float* __restrict__ z1part) {
    int hc = blockIdx.x;           // 16 (64 h each)
    int kc = blockIdx.y;           // 16 (64 k each)
    int tid = threadIdx.x;
    __shared__ float Wt[64][64];   // [k][h]
    __shared__ float Ht[64][64];   // [b][k]
    #pragma unroll
    for (int i = 0; i < 16; ++i) {
        int idx = tid + i * 256;
        int a = idx >> 6, c = idx & 63;
        Wt[a][c] = W1[(kc * 64 + a) * 1024 + hc * 64 + c];
        Ht[a][c] = h0[a * 1024 + kc * 64 + c];
    }
    __syncthreads();
    int h = tid & 63, bg = tid >> 6;    // 4 b-groups x 16 b
    float acc[16];
    #pragma unroll
    for (int i = 0; i < 16; ++i) acc[i] = 0.f;
    for (int k = 0; k < 64; k += 4) {
        float w0_ = Wt[k][h], w1_ = Wt[k + 1][h], w2_ = Wt[k + 2][h], w3_ = Wt[k + 3][h];
        #pragma unroll
        for (int bb = 0; bb < 16; ++bb) {
            float4 hv = *(const float4*)&Ht[bg * 16 + bb][k];
            acc[bb] += hv.x * w0_ + hv.y * w1_ + hv.z * w2_ + hv.w * w3_;
        }
    }
    #pragma unroll
    for (int bb = 0; bb < 16; ++bb) {
        int b = bg * 16 + bb;
        z1part[(kc * 64 + b) * 1024 + hc * 64 + h] = acc[bb];
    }
}

// K4b: h1 = relu(b1 + sum_kc z1part)
__global__ __launch_bounds__(256) void k4b_reduce(const float* __restrict__ z1part,
                                                  const float* __restrict__ b1,
                                                  float* __restrict__ h1) {
    int idx = blockIdx.x * 256 + threadIdx.x;   // 65536
    int h = idx & 1023;
    float acc = b1[h];
    #pragma unroll
    for (int kc = 0; kc < 16; ++kc) acc += z1part[kc * 65536 + idx];
    h1[idx] = fmaxf(acc, 0.f);
}

// K5: out[b] = sum_h h1[b][h]*Wo[h] + bo
__global__ __launch_bounds__(256) void k5_out(const float* __restrict__ h1,
                                              const float* __restrict__ Wo,
                                              const float* __restrict__ bo,
                                              float* __restrict__ out) {
    int b = blockIdx.x;
    int tid = threadIdx.x;
    float acc = 0.f;
    #pragma unroll
    for (int i = 0; i < 4; ++i) {
        int h = tid + i * 256;
        acc += h1[b * 1024 + h] * Wo[h];
    }
    #pragma unroll
    for (int off = 32; off >= 1; off >>= 1) acc += __shfl_down(acc, off);
    __shared__ float red[4];
    if ((tid & 63) == 0) red[tid >> 6] = acc;
    __syncthreads();
    if (tid == 0) out[b] = red[0] + red[1] + red[2] + red[3] + bo[0];
}

extern "C" void kernel_launch(void* const* d_in, const int* in_sizes, int n_in,
                              void* d_out, int out_size, void* d_ws, size_t ws_size,
                              hipStream_t stream) {
    const int*   x     = (const int*)d_in[0];    // (64,128) 0/1
    const int*   masks = (const int*)d_in[1];    // (3,128) 0/1
    const float* W0    = (const float*)d_in[2];  // (8256,1024)
    const float* b0    = (const float*)d_in[3];  // (1024)
    const float* W1    = (const float*)d_in[4];  // (1024,1024)
    const float* b1    = (const float*)d_in[5];  // (1024)
    const float* Wo    = (const float*)d_in[6];  // (1024,1)
    const float* bo    = (const float*)d_in[7];  // (1)
    float* out = (float*)d_out;                  // (64,1)

    char* ws = (char*)d_ws;
    float* S      = (float*)(ws);                      // 64*128*4      = 32 KB
    float* Apart  = (float*)(ws + (32u << 10));        // 128*1024*4    = 512 KB
    float* G      = (float*)(ws + (544u << 10));       // 128*1024*4    = 512 KB
    float* h0     = (float*)(ws + (1056u << 10));      // 64*1024*4     = 256 KB
    float* z1part = (float*)(ws + (1312u << 10));      // 16*64*1024*4  = 4 MB
    float* h1     = (float*)(ws + (5408u << 10));      // 64*1024*4     = 256 KB

    k1_S<<<1, 512, 0, stream>>>(x, S);
    k2_reduceW0<<<dim3(4, 128), 256, 0, stream>>>(W0, masks, Apart, G);
    k3_layer1<<<dim3(64, 4), 256, 0, stream>>>(Apart, G, S, b0, h0);
    k4_layer2<<<dim3(16, 16), 256, 0, stream>>>(h0, W1, z1part);
    k4b_reduce<<<256, 256, 0, stream>>>(z1part, b1, h1);
    k5_out<<<64, 256, 0, stream>>>(h1, Wo, bo, out);
}

// Round 2
// 39.006 us; speedup vs baseline: 1.2403x; 1.2403x over previous
//
#include <hip/hip_runtime.h>
#include <cstdint>

#define DEVFN __device__ __forceinline__

struct U128 { unsigned long long lo, hi; };

// rotate right by s (1..127): bit q of result = bit (q+s)%128 of w
DEVFN U128 rotr128(U128 w, int s) {
    U128 r;
    if (s == 64) { r.lo = w.hi; r.hi = w.lo; return r; }
    if (s < 64) {
        r.lo = (w.lo >> s) | (w.hi << (64 - s));
        r.hi = (w.hi >> s) | (w.lo << (64 - s));
    } else {
        int t = s - 64;
        unsigned long long lo = w.hi, hi = w.lo;
        r.lo = (lo >> t) | (hi << (64 - t));
        r.hi = (hi >> t) | (lo << (64 - t));
    }
    return r;
}

// logical shift right by s (1..127)
DEVFN U128 shr128(U128 w, int s) {
    U128 r;
    if (s == 64) { r.lo = w.hi; r.hi = 0ull; return r; }
    if (s < 64) {
        r.lo = (w.lo >> s) | (w.hi << (64 - s));
        r.hi = w.hi >> s;
    } else {
        r.lo = w.hi >> (s - 64); r.hi = 0ull;
    }
    return r;
}

// KB: fused {S computation (block 768)} + {balanced W0 reduction (blocks 0..767)}
// W0 reduction: A2/G2 slices. For r<64: slice0 = j in [0,64), slice1 = j in [64,128-r)
// stored at rows r and 128+r. For r>=64: single segment at row r (slice1 never read).
__global__ __launch_bounds__(256) void kB(const int* __restrict__ x,
                                          const int* __restrict__ masks,
                                          const float* __restrict__ W0,
                                          float* __restrict__ S,
                                          float* __restrict__ A2,
                                          float* __restrict__ G2) {
    int bid = blockIdx.x;
    int tid = threadIdx.x;

    if (bid == 768) {
        // S[b][r] = 2 * (r==0 ? pc_r : 128 - pc_r), pc_r = popcount(Dc^r(x_b))
        int b = tid >> 2;        // 64 rows of x
        int rc = tid & 3;        // 4 chunks of 32 r's
        const int* xb = x + b * 128;
        U128 w; w.lo = 0ull; w.hi = 0ull;
        #pragma unroll
        for (int p = 0; p < 64; ++p) w.lo |= (unsigned long long)(xb[p] & 1) << p;
        #pragma unroll
        for (int p = 0; p < 64; ++p) w.hi |= (unsigned long long)(xb[64 + p] & 1) << p;
        int r0 = rc * 32;
        if (r0 & 32) { U128 t = rotr128(w, 32); w.lo ^= t.lo; w.hi ^= t.hi; }
        if (r0 & 64) { U128 t = rotr128(w, 64); w.lo ^= t.lo; w.hi ^= t.hi; }
        for (int rr = 0; rr < 32; ++rr) {
            int r = r0 + rr;
            int pc = __popcll(w.lo) + __popcll(w.hi);
            int sv = (r == 0) ? pc : (128 - pc);
            S[b * 128 + r] = (float)(2 * sv);
            U128 t = rotr128(w, 1);
            w.lo ^= t.lo; w.hi ^= t.hi;
        }
        return;
    }

    int hc = bid & 3;            // 4 chunks of 256 h
    int y  = bid >> 2;           // 0..191 (r, segment) task
    int r, jstart, jend, slice;
    if (y < 128) { r = y >> 1; slice = y & 1; jstart = slice * 64; jend = (slice == 0) ? 64 : (128 - r); }
    else         { r = y - 64;  slice = 0;    jstart = 0;          jend = 128 - r; }

    int h = hc * 256 + tid;

    __shared__ unsigned long long mw[3][2];
    __shared__ float cA[64], cG[64];

    if (tid < 128) {             // two full waves -> ballot safe
        int half = tid >> 6;
        int lane = tid & 63;
        #pragma unroll
        for (int k = 0; k < 3; ++k) {
            unsigned long long bal = __ballot(masks[k * 128 + half * 64 + lane] & 1);
            if (lane == 0) mw[k][half] = bal;
        }
    }
    __syncthreads();
    if (tid < 64) {
        int j = jstart + tid;    // global feature position
        int c = 0;
        #pragma unroll
        for (int k = 0; k < 3; ++k) {
            U128 m; m.lo = mw[k][0]; m.hi = mw[k][1];
            #pragma unroll
            for (int s = 1; s <= 64; s <<= 1) {
                if (r & s) { U128 t = shr128(m, s); m.lo ^= t.lo; m.hi ^= t.hi; }
            }
            int bit = (j < 64) ? (int)((m.lo >> j) & 1) : (int)((m.hi >> (j - 64)) & 1);
            c += bit;
        }
        cA[tid] = 0.5f * (float)c - 1.0f;
        cG[tid] = (float)(2 - c) * (1.0f / 256.0f);
    }
    __syncthreads();

    int off = r * 128 - (r * (r - 1)) / 2;   // t-row offset for this r
    const float* p = W0 + (off + jstart) * 1024 + h;
    int L = jend - jstart;                    // <= 64
    float accA = 0.f, accG = 0.f;
    #pragma unroll 8
    for (int j = 0; j < L; ++j) {
        float w = p[j * 1024];
        accA += cA[j] * w;
        accG += cG[j] * w;
    }
    int row = slice * 128 + r;
    A2[row * 1024 + h] = accA;
    G2[row * 1024 + h] = accG;
}

// KC: h0[b][h] = relu(b0[h] + sum_r (A[r][h] + S[b][r]*G[r][h])), slices summed inline
__global__ __launch_bounds__(256) void kC(const float* __restrict__ A2,
                                          const float* __restrict__ G2,
                                          const float* __restrict__ S,
                                          const float* __restrict__ b0,
                                          float* __restrict__ h0) {
    int b  = blockIdx.x;          // 64
    int ht = blockIdx.y;          // 4
    int tid = threadIdx.x;
    int h = ht * 256 + tid;
    __shared__ float Srow[128];
    if (tid < 128) Srow[tid] = S[b * 128 + tid];
    __syncthreads();
    float acc = b0[h];
    #pragma unroll 8
    for (int r = 0; r < 64; ++r) {
        float a = A2[r * 1024 + h] + A2[(128 + r) * 1024 + h];
        float g = G2[r * 1024 + h] + G2[(128 + r) * 1024 + h];
        acc += a + Srow[r] * g;
    }
    #pragma unroll 8
    for (int r = 64; r < 128; ++r) {
        acc += A2[r * 1024 + h] + Srow[r] * G2[r * 1024 + h];
    }
    h0[b * 1024 + h] = fmaxf(acc, 0.f);
}

// KD: split-K GEMM partials: z1part[kc][b][h] = sum_{k in chunk} h0[b][k] * W1[k][h]
__global__ __launch_bounds__(256) void kD(const float* __restrict__ h0,
                                          const float* __restrict__ W1,
                                          float* __restrict__ z1part) {
    int hc = blockIdx.x;           // 16 (64 h each)
    int kc = blockIdx.y;           // 16 (64 k each)
    int tid = threadIdx.x;
    __shared__ float Wt[64][64];   // [k][h]
    __shared__ float Ht[64][64];   // [b][k]
    #pragma unroll
    for (int i = 0; i < 16; ++i) {
        int idx = tid + i * 256;
        int a = idx >> 6, c = idx & 63;
        Wt[a][c] = W1[(kc * 64 + a) * 1024 + hc * 64 + c];
        Ht[a][c] = h0[a * 1024 + kc * 64 + c];
    }
    __syncthreads();
    int h = tid & 63, bg = tid >> 6;    // 4 b-groups x 16 b
    float acc[16];
    #pragma unroll
    for (int i = 0; i < 16; ++i) acc[i] = 0.f;
    for (int k = 0; k < 64; k += 4) {
        float w0_ = Wt[k][h], w1_ = Wt[k + 1][h], w2_ = Wt[k + 2][h], w3_ = Wt[k + 3][h];
        #pragma unroll
        for (int bb = 0; bb < 16; ++bb) {
            float4 hv = *(const float4*)&Ht[bg * 16 + bb][k];
            acc[bb] += hv.x * w0_ + hv.y * w1_ + hv.z * w2_ + hv.w * w3_;
        }
    }
    #pragma unroll
    for (int bb = 0; bb < 16; ++bb) {
        int b = bg * 16 + bb;
        z1part[(kc * 64 + b) * 1024 + hc * 64 + h] = acc[bb];
    }
}

// KE: out[b] = sum_h relu(b1[h] + sum_kc z1part[kc][b][h]) * Wo[h] + bo
__global__ __launch_bounds__(256) void kE(const float* __restrict__ z1part,
                                          const float* __restrict__ b1,
                                          const float* __restrict__ Wo,
                                          const float* __restrict__ bo,
                                          float* __restrict__ out) {
    int b = blockIdx.x;
    int tid = threadIdx.x;
    float acc = 0.f;
    #pragma unroll
    for (int i = 0; i < 4; ++i) {
        int h = tid + i * 256;
        float z = b1[h];
        #pragma unroll
        for (int kc = 0; kc < 16; ++kc) z += z1part[(kc * 64 + b) * 1024 + h];
        acc += fmaxf(z, 0.f) * Wo[h];
    }
    #pragma unroll
    for (int off = 32; off >= 1; off >>= 1) acc += __shfl_down(acc, off);
    __shared__ float red[4];
    if ((tid & 63) == 0) red[tid >> 6] = acc;
    __syncthreads();
    if (tid == 0) out[b] = red[0] + red[1] + red[2] + red[3] + bo[0];
}

extern "C" void kernel_launch(void* const* d_in, const int* in_sizes, int n_in,
                              void* d_out, int out_size, void* d_ws, size_t ws_size,
                              hipStream_t stream) {
    const int*   x     = (const int*)d_in[0];    // (64,128) 0/1
    const int*   masks = (const int*)d_in[1];    // (3,128) 0/1
    const float* W0    = (const float*)d_in[2];  // (8256,1024)
    const float* b0    = (const float*)d_in[3];  // (1024)
    const float* W1    = (const float*)d_in[4];  // (1024,1024)
    const float* b1    = (const float*)d_in[5];  // (1024)
    const float* Wo    = (const float*)d_in[6];  // (1024,1)
    const float* bo    = (const float*)d_in[7];  // (1)
    float* out = (float*)d_out;                  // (64,1)

    char* ws = (char*)d_ws;
    float* S      = (float*)(ws);                      // 64*128*4      = 32 KB
    float* A2     = (float*)(ws + (32u   << 10));      // 192*1024*4    = 768 KB
    float* G2     = (float*)(ws + (800u  << 10));      // 192*1024*4    = 768 KB
    float* h0     = (float*)(ws + (1568u << 10));      // 64*1024*4     = 256 KB
    float* z1part = (float*)(ws + (1824u << 10));      // 16*64*1024*4  = 4 MB

    kB<<<769, 256, 0, stream>>>(x, masks, W0, S, A2, G2);
    kC<<<dim3(64, 4), 256, 0, stream>>>(A2, G2, S, b0, h0);
    kD<<<dim3(16, 16), 256, 0, stream>>>(h0, W1, z1part);
    kE<<<64, 256, 0, stream>>>(z1part, b1, Wo, bo, out);
}